// Round 1
// baseline (931.809 us; speedup 1.0000x reference)
//
#include <hip/hip_runtime.h>
#include <math.h>

#define MAXDEG 512

// ---------------- block reduce helpers ----------------
__device__ __forceinline__ float blockReduceSum(float v) {
    __shared__ float sh[8];
    int lane = threadIdx.x & 63, w = threadIdx.x >> 6;
    for (int o = 32; o > 0; o >>= 1) v += __shfl_down(v, o);
    __syncthreads();
    if (lane == 0) sh[w] = v;
    __syncthreads();
    if (w == 0) {
        int nw = (blockDim.x + 63) >> 6;
        v = (lane < nw) ? sh[lane] : 0.f;
        for (int o = 4; o > 0; o >>= 1) v += __shfl_down(v, o);
        if (lane == 0) sh[0] = v;
    }
    __syncthreads();
    return sh[0];
}

__device__ __forceinline__ float blockReduceMax(float v) {
    __shared__ float sh[8];
    int lane = threadIdx.x & 63, w = threadIdx.x >> 6;
    for (int o = 32; o > 0; o >>= 1) v = fmaxf(v, __shfl_down(v, o));
    __syncthreads();
    if (lane == 0) sh[w] = v;
    __syncthreads();
    if (w == 0) {
        int nw = (blockDim.x + 63) >> 6;
        v = (lane < nw) ? sh[lane] : -3.4e38f;
        for (int o = 4; o > 0; o >>= 1) v = fmaxf(v, __shfl_down(v, o));
        if (lane == 0) sh[0] = v;
    }
    __syncthreads();
    return sh[0];
}

// ---------------- kernels ----------------

// Build CSR-ish neighbor lists (fixed stride MAXDEG). adj identical across all
// attention layers, so do this once. Order within a row is nondeterministic;
// only affects fp summation order (threshold is ~2% — irrelevant).
__global__ void build_csr(const float* __restrict__ adj, int* __restrict__ colIdx,
                          int* __restrict__ deg, int N) {
    int row = blockIdx.x;
    __shared__ int cnt;
    if (threadIdx.x == 0) cnt = 0;
    __syncthreads();
    const float* ar = adj + (size_t)row * N;
    int* outp = colIdx + (size_t)row * MAXDEG;
    for (int j = threadIdx.x; j < N; j += blockDim.x) {
        if (ar[j] > 0.f) {
            int p = atomicAdd(&cnt, 1);
            if (p < MAXDEG) outp[p] = j;
        }
    }
    __syncthreads();
    if (threadIdx.x == 0) deg[row] = cnt < MAXDEG ? cnt : MAXDEG;
}

__global__ void rowsum_kernel(const float* __restrict__ s, float* __restrict__ dv, int N) {
    int row = blockIdx.x;
    const float* r = s + (size_t)row * N;
    float p = 0.f;
    for (int j = threadIdx.x; j < N; j += blockDim.x) p += r[j];
    p = blockReduceSum(p);
    if (threadIdx.x == 0) dv[row] = p;
}

__global__ void hin_kernel(const float* __restrict__ x, const int* __restrict__ obs,
                           const float* __restrict__ theta, float* __restrict__ hin,
                           int N, int F) {
    size_t i = (size_t)blockIdx.x * blockDim.x + threadIdx.x;
    if (i >= (size_t)N * F) return;
    int n = (int)(i / F), f = (int)(i % F);
    float v = x[i];
    if (obs[n] == 1) v += theta[f];
    hin[i] = v;
}

// C[b] = A[b] @ W[b].  A:[N,K] row-major (batch stride sA, 0 = shared),
// W:[K,M] row-major (stride sW), C:[N,M] (stride sC).
// Requires N%32==0, K%32==0, M%32==0.
__global__ void gemm32(const float* __restrict__ A, const float* __restrict__ W,
                       float* __restrict__ C, int N, int K, int M,
                       size_t sA, size_t sW, size_t sC) {
    int b = blockIdx.z;
    A += (size_t)b * sA; W += (size_t)b * sW; C += (size_t)b * sC;
    __shared__ float As[32][33];   // As[k][m]
    __shared__ float Bs[32][33];   // Bs[k][n]
    const int tid = threadIdx.x;
    const int row0 = blockIdx.y * 32, col0 = blockIdx.x * 32;
    const int lr = tid >> 3;            // 0..31
    const int lc4 = (tid & 7) << 2;     // 0,4,..,28
    const int c = tid & 31;             // output col in tile
    const int r0 = (tid >> 5) << 2;     // output row base in tile
    float acc[4] = {0.f, 0.f, 0.f, 0.f};
    const int nk = K >> 5;
    for (int kt = 0; kt < nk; kt++) {
        const int k0 = kt << 5;
        // load A tile (transpose into As[k][m])
        const float4 av = *(const float4*)(A + (size_t)(row0 + lr) * K + k0 + lc4);
        As[lc4 + 0][lr] = av.x; As[lc4 + 1][lr] = av.y;
        As[lc4 + 2][lr] = av.z; As[lc4 + 3][lr] = av.w;
        // load W tile
        const float4 bv = *(const float4*)(W + (size_t)(k0 + lr) * M + col0 + lc4);
        Bs[lr][lc4 + 0] = bv.x; Bs[lr][lc4 + 1] = bv.y;
        Bs[lr][lc4 + 2] = bv.z; Bs[lr][lc4 + 3] = bv.w;
        __syncthreads();
        #pragma unroll
        for (int k = 0; k < 32; k++) {
            float w0 = Bs[k][c];
            acc[0] += As[k][r0 + 0] * w0;
            acc[1] += As[k][r0 + 1] * w0;
            acc[2] += As[k][r0 + 2] * w0;
            acc[3] += As[k][r0 + 3] * w0;
        }
        __syncthreads();
    }
    #pragma unroll
    for (int i = 0; i < 4; i++)
        C[(size_t)(row0 + r0 + i) * M + col0 + c] = acc[i];
}

// el[b,n] = Wh[b,n,:]·a[b,0:D] ; er[b,n] = Wh[b,n,:]·a[b,D:2D]
__global__ void eler_kernel(const float* __restrict__ Wh, const float* __restrict__ a,
                            float* __restrict__ el, float* __restrict__ er,
                            int N, int D, size_t sWh, size_t sa) {
    int row = blockIdx.x, b = blockIdx.y;
    const float* w = Wh + (size_t)b * sWh + (size_t)row * D;
    const float* ab = a + (size_t)b * sa;
    float p0 = 0.f, p1 = 0.f;
    for (int d = threadIdx.x; d < D; d += blockDim.x) {
        float v = w[d];
        p0 += v * ab[d];
        p1 += v * ab[D + d];
    }
    p0 = blockReduceSum(p0);
    p1 = blockReduceSum(p1);
    if (threadIdx.x == 0) { el[(size_t)b * N + row] = p0; er[(size_t)b * N + row] = p1; }
}

// One block per (row, batch). Masked-softmax over neighbors, then gather
// out[row,:] = sum_j p_j * Wh[j,:] / l.   act: 0=none, 1=elu.
__global__ void attn_kernel(const float* __restrict__ Wh, const float* __restrict__ el,
                            const float* __restrict__ er, const int* __restrict__ colIdx,
                            const int* __restrict__ deg, float* __restrict__ out,
                            int N, int D, size_t sWh, size_t sOut, int outRowStride, int act) {
    int row = blockIdx.x, b = blockIdx.y, tid = threadIdx.x;
    const float* whb = Wh + (size_t)b * sWh;
    const float* erb = er + (size_t)b * N;
    const float eln = el[(size_t)b * N + row];
    const int dc = deg[row];
    const int* ci = colIdx + (size_t)row * MAXDEG;
    __shared__ float sp[MAXDEG];
    __shared__ int sc[MAXDEG];
    float m = -3.4e38f;
    for (int k = tid; k < dc; k += blockDim.x) {
        int j = ci[k];
        sc[k] = j;
        float s = eln + erb[j];
        s = (s >= 0.f) ? s : 0.2f * s;        // LeakyReLU(0.2)
        sp[k] = s;
        m = fmaxf(m, s);
    }
    m = blockReduceMax(m);
    float l = 0.f;
    for (int k = tid; k < dc; k += blockDim.x) {
        float p = __expf(sp[k] - m);
        sp[k] = p;
        l += p;
    }
    l = blockReduceSum(l);
    const float inv = 1.f / l;
    for (int d = tid; d < D; d += blockDim.x) {
        float acc = 0.f;
        for (int k = 0; k < dc; k++)
            acc += sp[k] * whb[(size_t)sc[k] * D + d];
        float v = acc * inv;
        if (act == 1) v = (v > 0.f) ? v : expm1f(v);   // ELU
        out[(size_t)b * sOut + (size_t)row * outRowStride + d] = v;
    }
}

// o2Wh[n] = o1out[n,:64] · Wo1[:,0]   (block = 64 threads = 1 wave)
__global__ void matvec64_kernel(const float* __restrict__ h3, const float* __restrict__ w,
                                float* __restrict__ out, int N) {
    int row = blockIdx.x;
    float v = h3[(size_t)row * 64 + threadIdx.x] * w[threadIdx.x];
    for (int o = 32; o > 0; o >>= 1) v += __shfl_down(v, o);
    if (threadIdx.x == 0) out[row] = v;
}

__device__ __forceinline__ float leaky(float x) { return x >= 0.f ? x : 0.2f * x; }

__global__ void degree_nn(const float* __restrict__ h4, const float* __restrict__ dv,
                          const float* __restrict__ dW, const float* __restrict__ dW0,
                          const float* __restrict__ dW1, const float* __restrict__ dW01,
                          const float* __restrict__ dW2, const float* __restrict__ dW02,
                          const float* __restrict__ dV, const float* __restrict__ dV0,
                          float* __restrict__ out, int N) {
    int n = blockIdx.x * blockDim.x + threadIdx.x;
    if (n >= N) return;
    float h = h4[n];
    h = (h > 0.f) ? h : expm1f(h);            // elu
    float d = dv[n];
    float t0[10], t1[20], t2[10];
    #pragma unroll
    for (int i = 0; i < 10; i++)
        t0[i] = leaky(h * dW[i] + d * dW[10 + i] + dW0[i]);
    #pragma unroll
    for (int j = 0; j < 20; j++) {
        float s = dW01[j];
        #pragma unroll
        for (int i = 0; i < 10; i++) s += t0[i] * dW1[i * 20 + j];
        t1[j] = leaky(s);
    }
    #pragma unroll
    for (int j = 0; j < 10; j++) {
        float s = dW02[j];
        #pragma unroll
        for (int i = 0; i < 20; i++) s += t1[i] * dW2[i * 10 + j];
        t2[j] = leaky(s);
    }
    float o = dV0[0];
    #pragma unroll
    for (int i = 0; i < 10; i++) o += t2[i] * dV[i];
    out[n] = leaky(o);
}

// ---------------- launch ----------------
extern "C" void kernel_launch(void* const* d_in, const int* in_sizes, int n_in,
                              void* d_out, int out_size, void* d_ws, size_t ws_size,
                              hipStream_t stream) {
    const int N = 4096, F = 512, H = 4, D1 = 256, O1 = 64;
    const float* x     = (const float*)d_in[0];
    const float* adj   = (const float*)d_in[1];
    const int*   obs   = (const int*)  d_in[2];
    const float* s_mat = (const float*)d_in[3];
    const float* theta = (const float*)d_in[4];
    const float* Wh0   = (const float*)d_in[5];
    const float* ah0   = (const float*)d_in[6];
    const float* Wh1   = (const float*)d_in[7];
    const float* ah1   = (const float*)d_in[8];
    const float* Wo0   = (const float*)d_in[9];
    const float* ao0   = (const float*)d_in[10];
    const float* ao1   = (const float*)d_in[12];
    const float* Wo1   = (const float*)d_in[11];
    const float* dWp   = (const float*)d_in[13];
    const float* dW0p  = (const float*)d_in[14];
    const float* dW1p  = (const float*)d_in[15];
    const float* dW01p = (const float*)d_in[16];
    const float* dW2p  = (const float*)d_in[17];
    const float* dW02p = (const float*)d_in[18];
    const float* dVp   = (const float*)d_in[19];
    const float* dV0p  = (const float*)d_in[20];
    float* outp = (float*)d_out;

    char* ws = (char*)d_ws;
    auto alloc = [&](size_t bytes) {
        char* p = ws;
        ws += (bytes + 255) & ~(size_t)255;
        return p;
    };
    float* hin  = (float*)alloc((size_t)N * F * 4);
    float* whA  = (float*)alloc((size_t)H * N * D1 * 4);
    float* hb   = (float*)alloc((size_t)H * N * D1 * 4);
    float* hcat = (float*)alloc((size_t)N * H * D1 * 4);
    float* o1Wh = (float*)alloc((size_t)N * O1 * 4);
    float* o1o  = (float*)alloc((size_t)N * O1 * 4);
    float* o2Wh = (float*)alloc((size_t)N * 4);
    float* o2o  = (float*)alloc((size_t)N * 4);
    float* el   = (float*)alloc((size_t)H * N * 4);
    float* er   = (float*)alloc((size_t)H * N * 4);
    float* dv   = (float*)alloc((size_t)N * 4);
    int*   colIdx = (int*)alloc((size_t)N * MAXDEG * 4);
    int*   deg    = (int*)alloc((size_t)N * 4);

    build_csr<<<N, 256, 0, stream>>>(adj, colIdx, deg, N);
    rowsum_kernel<<<N, 256, 0, stream>>>(s_mat, dv, N);
    hin_kernel<<<(N * F + 255) / 256, 256, 0, stream>>>(x, obs, theta, hin, N, F);

    // ----- multi-head layer 1 (D=256, elu) -----
    gemm32<<<dim3(D1 / 32, N / 32, H), 256, 0, stream>>>(
        hin, Wh0, whA, N, F, D1, 0, (size_t)F * D1, (size_t)N * D1);
    eler_kernel<<<dim3(N, H), 256, 0, stream>>>(whA, ah0, el, er, N, D1,
        (size_t)N * D1, (size_t)2 * D1);
    attn_kernel<<<dim3(N, H), 256, 0, stream>>>(whA, el, er, colIdx, deg, hb,
        N, D1, (size_t)N * D1, (size_t)N * D1, D1, 1);

    // ----- multi-head layer 2 (D=256, elu), output interleaved as hcat -----
    gemm32<<<dim3(D1 / 32, N / 32, H), 256, 0, stream>>>(
        hb, Wh1, whA, N, D1, D1, (size_t)N * D1, (size_t)D1 * D1, (size_t)N * D1);
    eler_kernel<<<dim3(N, H), 256, 0, stream>>>(whA, ah1, el, er, N, D1,
        (size_t)N * D1, (size_t)2 * D1);
    attn_kernel<<<dim3(N, H), 256, 0, stream>>>(whA, el, er, colIdx, deg, hcat,
        N, D1, (size_t)N * D1, (size_t)D1, H * D1, 1);

    // ----- output layer 1 (D=64, no act) -----
    gemm32<<<dim3(O1 / 32, N / 32, 1), 256, 0, stream>>>(
        hcat, Wo0, o1Wh, N, H * D1, O1, 0, 0, 0);
    eler_kernel<<<dim3(N, 1), 256, 0, stream>>>(o1Wh, ao0, el, er, N, O1, 0, 0);
    attn_kernel<<<dim3(N, 1), 256, 0, stream>>>(o1Wh, el, er, colIdx, deg, o1o,
        N, O1, 0, 0, O1, 0);

    // ----- output layer 2 (D=1, no act) -----
    matvec64_kernel<<<N, 64, 0, stream>>>(o1o, Wo1, o2Wh, N);
    eler_kernel<<<dim3(N, 1), 256, 0, stream>>>(o2Wh, ao1, el, er, N, 1, 0, 0);
    attn_kernel<<<dim3(N, 1), 256, 0, stream>>>(o2Wh, el, er, colIdx, deg, o2o,
        N, 1, 0, 0, 1, 0);

    // ----- elu + degreeNN -----
    degree_nn<<<(N + 255) / 256, 256, 0, stream>>>(o2o, dv, dWp, dW0p, dW1p,
        dW01p, dW2p, dW02p, dVp, dV0p, outp, N);
}

// Round 2
// 648.421 us; speedup vs baseline: 1.4370x; 1.4370x over previous
//
#include <hip/hip_runtime.h>
#include <hip/hip_bf16.h>
#include <math.h>

#define MAXDEG 512

typedef short v8s __attribute__((ext_vector_type(8)));
typedef float v4f __attribute__((ext_vector_type(4)));

// ---------------- block reduce helpers ----------------
__device__ __forceinline__ float blockReduceSum(float v) {
    __shared__ float sh[8];
    int lane = threadIdx.x & 63, w = threadIdx.x >> 6;
    for (int o = 32; o > 0; o >>= 1) v += __shfl_down(v, o);
    __syncthreads();
    if (lane == 0) sh[w] = v;
    __syncthreads();
    if (w == 0) {
        int nw = (blockDim.x + 63) >> 6;
        v = (lane < nw) ? sh[lane] : 0.f;
        for (int o = 4; o > 0; o >>= 1) v += __shfl_down(v, o);
        if (lane == 0) sh[0] = v;
    }
    __syncthreads();
    return sh[0];
}

__device__ __forceinline__ float blockReduceMax(float v) {
    __shared__ float sh[8];
    int lane = threadIdx.x & 63, w = threadIdx.x >> 6;
    for (int o = 32; o > 0; o >>= 1) v = fmaxf(v, __shfl_down(v, o));
    __syncthreads();
    if (lane == 0) sh[w] = v;
    __syncthreads();
    if (w == 0) {
        int nw = (blockDim.x + 63) >> 6;
        v = (lane < nw) ? sh[lane] : -3.4e38f;
        for (int o = 4; o > 0; o >>= 1) v = fmaxf(v, __shfl_down(v, o));
        if (lane == 0) sh[0] = v;
    }
    __syncthreads();
    return sh[0];
}

// ---------------- kernels ----------------

__global__ void build_csr(const float* __restrict__ adj, int* __restrict__ colIdx,
                          int* __restrict__ deg, int N) {
    int row = blockIdx.x;
    __shared__ int cnt;
    if (threadIdx.x == 0) cnt = 0;
    __syncthreads();
    const float* ar = adj + (size_t)row * N;
    int* outp = colIdx + (size_t)row * MAXDEG;
    for (int j = threadIdx.x; j < N; j += blockDim.x) {
        if (ar[j] > 0.f) {
            int p = atomicAdd(&cnt, 1);
            if (p < MAXDEG) outp[p] = j;
        }
    }
    __syncthreads();
    if (threadIdx.x == 0) deg[row] = cnt < MAXDEG ? cnt : MAXDEG;
}

__global__ void rowsum_kernel(const float* __restrict__ s, float* __restrict__ dv, int N) {
    int row = blockIdx.x;
    const float* r = s + (size_t)row * N;
    float p = 0.f;
    for (int j = threadIdx.x; j < N; j += blockDim.x) p += r[j];
    p = blockReduceSum(p);
    if (threadIdx.x == 0) dv[row] = p;
}

__global__ void hin_kernel(const float* __restrict__ x, const int* __restrict__ obs,
                           const float* __restrict__ theta, __hip_bfloat16* __restrict__ hin,
                           int N, int F) {
    size_t i = (size_t)blockIdx.x * blockDim.x + threadIdx.x;
    if (i >= (size_t)N * F) return;
    int n = (int)(i / F), f = (int)(i % F);
    float v = x[i];
    if (obs[n] == 1) v += theta[f];
    hin[i] = __float2bfloat16(v);
}

// Wt[b][m][k] = bf16(W[b][k][m])
__global__ void conv_wt(const float* __restrict__ W, __hip_bfloat16* __restrict__ Wt,
                        int K, int M) {
    int b = blockIdx.y;
    size_t i = (size_t)blockIdx.x * 256 + threadIdx.x;
    if (i >= (size_t)M * K) return;
    int mm = (int)(i / K), kk = (int)(i % K);
    Wt[(size_t)b * M * K + i] = __float2bfloat16(W[(size_t)b * K * M + (size_t)kk * M + mm]);
}

// C[b] = A[b] @ Bt[b]^T.  A:[N,K] bf16 row-major, Bt:[M,K] bf16 row-major
// (weights pre-transposed), C:[N,M] bf16.  N%64==0, M%64==0, K%32==0.
// Block: 256 thr = 4 waves; block tile 64x64; wave w does rows w*16..+15.
__global__ __launch_bounds__(256) void gemm_mfma(
    const __hip_bfloat16* __restrict__ A, const __hip_bfloat16* __restrict__ Bt,
    __hip_bfloat16* __restrict__ C, int N, int K, int M,
    size_t sA, size_t sB, size_t sC) {
    int b = blockIdx.z;
    const unsigned short* Ag = (const unsigned short*)(A + (size_t)b * sA);
    const unsigned short* Bg = (const unsigned short*)(Bt + (size_t)b * sB);
    __hip_bfloat16* Cg = C + (size_t)b * sC;

    __shared__ __align__(16) unsigned short As[64][40];   // pad 32->40 (2-way free)
    __shared__ __align__(16) unsigned short Bs[64][40];   // Bs[n][k]

    const int tid = threadIdx.x;
    const int wave = tid >> 6, lane = tid & 63;
    const int row0 = blockIdx.y * 64, col0 = blockIdx.x * 64;
    const int sRow = tid >> 2;          // 0..63
    const int sOff = (tid & 3) * 8;     // 0,8,16,24
    const int m = lane & 15, quad = lane >> 4;

    v4f acc[4];
    #pragma unroll
    for (int c = 0; c < 4; c++) acc[c] = (v4f)(0.f);

    for (int k0 = 0; k0 < K; k0 += 32) {
        *(int4*)(&As[sRow][sOff]) =
            *(const int4*)(Ag + (size_t)(row0 + sRow) * K + k0 + sOff);
        *(int4*)(&Bs[sRow][sOff]) =
            *(const int4*)(Bg + (size_t)(col0 + sRow) * K + k0 + sOff);
        __syncthreads();
        v8s af = *(const v8s*)(&As[wave * 16 + m][quad * 8]);
        #pragma unroll
        for (int c = 0; c < 4; c++) {
            v8s bf = *(const v8s*)(&Bs[c * 16 + m][quad * 8]);
            acc[c] = __builtin_amdgcn_mfma_f32_16x16x32_bf16(af, bf, acc[c], 0, 0, 0);
        }
        __syncthreads();
    }
    #pragma unroll
    for (int c = 0; c < 4; c++)
        #pragma unroll
        for (int r = 0; r < 4; r++) {
            int row = row0 + wave * 16 + quad * 4 + r;
            int col = col0 + c * 16 + m;
            Cg[(size_t)row * M + col] = __float2bfloat16(acc[c][r]);
        }
}

// el[b,n] = Wh[b,n,:]·a[b,0:D] ; er[b,n] = Wh[b,n,:]·a[b,D:2D]
__global__ void eler_kernel(const __hip_bfloat16* __restrict__ Wh, const float* __restrict__ a,
                            float* __restrict__ el, float* __restrict__ er,
                            int N, int D, size_t sWh, size_t sa) {
    int row = blockIdx.x, b = blockIdx.y;
    const __hip_bfloat16* w = Wh + (size_t)b * sWh + (size_t)row * D;
    const float* ab = a + (size_t)b * sa;
    float p0 = 0.f, p1 = 0.f;
    for (int d = threadIdx.x; d < D; d += blockDim.x) {
        float v = __bfloat162float(w[d]);
        p0 += v * ab[d];
        p1 += v * ab[D + d];
    }
    p0 = blockReduceSum(p0);
    p1 = blockReduceSum(p1);
    if (threadIdx.x == 0) { el[(size_t)b * N + row] = p0; er[(size_t)b * N + row] = p1; }
}

// Masked softmax over neighbors + gather. act: 0=none, 1=elu.
__global__ void attn_kernel(const __hip_bfloat16* __restrict__ Wh, const float* __restrict__ el,
                            const float* __restrict__ er, const int* __restrict__ colIdx,
                            const int* __restrict__ deg, __hip_bfloat16* __restrict__ out,
                            int N, int D, size_t sWh, size_t sOut, int outRowStride, int act) {
    int row = blockIdx.x, b = blockIdx.y, tid = threadIdx.x;
    const __hip_bfloat16* whb = Wh + (size_t)b * sWh;
    const float* erb = er + (size_t)b * N;
    const float eln = el[(size_t)b * N + row];
    const int dc = deg[row];
    const int* ci = colIdx + (size_t)row * MAXDEG;
    __shared__ float sp[MAXDEG];
    __shared__ int sc[MAXDEG];
    float mx = -3.4e38f;
    for (int k = tid; k < dc; k += blockDim.x) {
        int j = ci[k];
        sc[k] = j;
        float s = eln + erb[j];
        s = (s >= 0.f) ? s : 0.2f * s;        // LeakyReLU(0.2)
        sp[k] = s;
        mx = fmaxf(mx, s);
    }
    mx = blockReduceMax(mx);
    float l = 0.f;
    for (int k = tid; k < dc; k += blockDim.x) {
        float p = __expf(sp[k] - mx);
        sp[k] = p;
        l += p;
    }
    l = blockReduceSum(l);
    const float inv = 1.f / l;

    if (D == 1) {
        float acc = 0.f;
        for (int k = tid; k < dc; k += blockDim.x)
            acc += sp[k] * __bfloat162float(whb[sc[k]]);
        acc = blockReduceSum(acc);
        if (tid == 0) {
            float v = acc * inv;
            if (act == 1) v = (v > 0.f) ? v : expm1f(v);
            out[(size_t)b * sOut + (size_t)row * outRowStride] = __float2bfloat16(v);
        }
        return;
    }

    for (int d = tid; d < D; d += blockDim.x) {
        float acc = 0.f;
        #pragma unroll 4
        for (int k = 0; k < dc; k++)
            acc += sp[k] * __bfloat162float(whb[(size_t)sc[k] * D + d]);
        float v = acc * inv;
        if (act == 1) v = (v > 0.f) ? v : expm1f(v);   // ELU
        out[(size_t)b * sOut + (size_t)row * outRowStride + d] = __float2bfloat16(v);
    }
}

// o2Wh[n] = o1o[n,:64] · Wo1[:,0]
__global__ void matvec64_kernel(const __hip_bfloat16* __restrict__ h3,
                                const float* __restrict__ w,
                                __hip_bfloat16* __restrict__ out, int N) {
    int row = blockIdx.x;
    float v = __bfloat162float(h3[(size_t)row * 64 + threadIdx.x]) * w[threadIdx.x];
    for (int o = 32; o > 0; o >>= 1) v += __shfl_down(v, o);
    if (threadIdx.x == 0) out[row] = __float2bfloat16(v);
}

__device__ __forceinline__ float leaky(float x) { return x >= 0.f ? x : 0.2f * x; }

__global__ void degree_nn(const __hip_bfloat16* __restrict__ h4, const float* __restrict__ dv,
                          const float* __restrict__ dW, const float* __restrict__ dW0,
                          const float* __restrict__ dW1, const float* __restrict__ dW01,
                          const float* __restrict__ dW2, const float* __restrict__ dW02,
                          const float* __restrict__ dV, const float* __restrict__ dV0,
                          float* __restrict__ out, int N) {
    int n = blockIdx.x * blockDim.x + threadIdx.x;
    if (n >= N) return;
    float h = __bfloat162float(h4[n]);
    h = (h > 0.f) ? h : expm1f(h);            // elu
    float d = dv[n];
    float t0[10], t1[20], t2[10];
    #pragma unroll
    for (int i = 0; i < 10; i++)
        t0[i] = leaky(h * dW[i] + d * dW[10 + i] + dW0[i]);
    #pragma unroll
    for (int j = 0; j < 20; j++) {
        float s = dW01[j];
        #pragma unroll
        for (int i = 0; i < 10; i++) s += t0[i] * dW1[i * 20 + j];
        t1[j] = leaky(s);
    }
    #pragma unroll
    for (int j = 0; j < 10; j++) {
        float s = dW02[j];
        #pragma unroll
        for (int i = 0; i < 20; i++) s += t1[i] * dW2[i * 10 + j];
        t2[j] = leaky(s);
    }
    float o = dV0[0];
    #pragma unroll
    for (int i = 0; i < 10; i++) o += t2[i] * dV[i];
    out[n] = leaky(o);
}

// ---------------- launch ----------------
extern "C" void kernel_launch(void* const* d_in, const int* in_sizes, int n_in,
                              void* d_out, int out_size, void* d_ws, size_t ws_size,
                              hipStream_t stream) {
    const int N = 4096, F = 512, H = 4, D1 = 256, O1 = 64;
    const float* x     = (const float*)d_in[0];
    const float* adj   = (const float*)d_in[1];
    const int*   obs   = (const int*)  d_in[2];
    const float* s_mat = (const float*)d_in[3];
    const float* theta = (const float*)d_in[4];
    const float* Wh0   = (const float*)d_in[5];
    const float* ah0   = (const float*)d_in[6];
    const float* Wh1   = (const float*)d_in[7];
    const float* ah1   = (const float*)d_in[8];
    const float* Wo0   = (const float*)d_in[9];
    const float* ao0   = (const float*)d_in[10];
    const float* Wo1   = (const float*)d_in[11];
    const float* ao1   = (const float*)d_in[12];
    const float* dWp   = (const float*)d_in[13];
    const float* dW0p  = (const float*)d_in[14];
    const float* dW1p  = (const float*)d_in[15];
    const float* dW01p = (const float*)d_in[16];
    const float* dW2p  = (const float*)d_in[17];
    const float* dW02p = (const float*)d_in[18];
    const float* dVp   = (const float*)d_in[19];
    const float* dV0p  = (const float*)d_in[20];
    float* outp = (float*)d_out;

    char* ws = (char*)d_ws;
    auto alloc = [&](size_t bytes) {
        char* p = ws;
        ws += (bytes + 255) & ~(size_t)255;
        return p;
    };
    typedef __hip_bfloat16 bf;
    bf* hin   = (bf*)alloc((size_t)N * F * 2);
    bf* whA   = (bf*)alloc((size_t)H * N * D1 * 2);
    bf* hb    = (bf*)alloc((size_t)H * N * D1 * 2);
    bf* hcat  = (bf*)alloc((size_t)N * H * D1 * 2);
    bf* o1Wh  = (bf*)alloc((size_t)N * O1 * 2);
    bf* o1o   = (bf*)alloc((size_t)N * O1 * 2);
    bf* o2Wh  = (bf*)alloc((size_t)N * 2);
    bf* o2o   = (bf*)alloc((size_t)N * 2);
    bf* Wh0t  = (bf*)alloc((size_t)H * F * D1 * 2);
    bf* Wh1t  = (bf*)alloc((size_t)H * D1 * D1 * 2);
    bf* Wo0t  = (bf*)alloc((size_t)H * D1 * O1 * 2);
    float* el = (float*)alloc((size_t)H * N * 4);
    float* er = (float*)alloc((size_t)H * N * 4);
    float* dv = (float*)alloc((size_t)N * 4);
    int* colIdx = (int*)alloc((size_t)N * MAXDEG * 4);
    int* deg    = (int*)alloc((size_t)N * 4);

    build_csr<<<N, 256, 0, stream>>>(adj, colIdx, deg, N);
    rowsum_kernel<<<N, 256, 0, stream>>>(s_mat, dv, N);
    hin_kernel<<<(N * F + 255) / 256, 256, 0, stream>>>(x, obs, theta, hin, N, F);
    conv_wt<<<dim3((F * D1 + 255) / 256, H), 256, 0, stream>>>(Wh0, Wh0t, F, D1);
    conv_wt<<<dim3((D1 * D1 + 255) / 256, H), 256, 0, stream>>>(Wh1, Wh1t, D1, D1);
    conv_wt<<<dim3((H * D1 * O1 + 255) / 256, 1), 256, 0, stream>>>(Wo0, Wo0t, H * D1, O1);

    // ----- multi-head layer 1 (D=256, elu) -----
    gemm_mfma<<<dim3(D1 / 64, N / 64, H), 256, 0, stream>>>(
        hin, Wh0t, whA, N, F, D1, 0, (size_t)D1 * F, (size_t)N * D1);
    eler_kernel<<<dim3(N, H), 256, 0, stream>>>(whA, ah0, el, er, N, D1,
        (size_t)N * D1, (size_t)2 * D1);
    attn_kernel<<<dim3(N, H), 256, 0, stream>>>(whA, el, er, colIdx, deg, hb,
        N, D1, (size_t)N * D1, (size_t)N * D1, D1, 1);

    // ----- multi-head layer 2 (D=256, elu) -> hcat interleaved -----
    gemm_mfma<<<dim3(D1 / 64, N / 64, H), 256, 0, stream>>>(
        hb, Wh1t, whA, N, D1, D1, (size_t)N * D1, (size_t)D1 * D1, (size_t)N * D1);
    eler_kernel<<<dim3(N, H), 256, 0, stream>>>(whA, ah1, el, er, N, D1,
        (size_t)N * D1, (size_t)2 * D1);
    attn_kernel<<<dim3(N, H), 256, 0, stream>>>(whA, el, er, colIdx, deg, hcat,
        N, D1, (size_t)N * D1, (size_t)D1, H * D1, 1);

    // ----- output layer 1 (D=64, no act) -----
    gemm_mfma<<<dim3(O1 / 64, N / 64, 1), 256, 0, stream>>>(
        hcat, Wo0t, o1Wh, N, H * D1, O1, 0, 0, 0);
    eler_kernel<<<dim3(N, 1), 64, 0, stream>>>(o1Wh, ao0, el, er, N, O1, 0, 0);
    attn_kernel<<<dim3(N, 1), 64, 0, stream>>>(o1Wh, el, er, colIdx, deg, o1o,
        N, O1, 0, 0, O1, 0);

    // ----- output layer 2 (D=1, no act) -----
    matvec64_kernel<<<N, 64, 0, stream>>>(o1o, Wo1, o2Wh, N);
    eler_kernel<<<dim3(N, 1), 64, 0, stream>>>(o2Wh, ao1, el, er, N, 1, 0, 0);
    attn_kernel<<<dim3(N, 1), 256, 0, stream>>>(o2Wh, el, er, colIdx, deg, o2o,
        N, 1, 0, 0, 1, 0);

    // ----- elu + degreeNN -----
    degree_nn<<<(N + 255) / 256, 256, 0, stream>>>(o2o, dv, dWp, dW0p, dW1p,
        dW01p, dW2p, dW02p, dVp, dV0p, outp, N);
}

// Round 3
// 491.776 us; speedup vs baseline: 1.8948x; 1.3185x over previous
//
#include <hip/hip_runtime.h>
#include <hip/hip_bf16.h>
#include <math.h>

#define MAXDEG 512

typedef short v8s __attribute__((ext_vector_type(8)));
typedef float v4f __attribute__((ext_vector_type(4)));

// ---------------- block reduce helpers ----------------
__device__ __forceinline__ float blockReduceSum(float v) {
    __shared__ float sh[8];
    int lane = threadIdx.x & 63, w = threadIdx.x >> 6;
    for (int o = 32; o > 0; o >>= 1) v += __shfl_down(v, o);
    __syncthreads();
    if (lane == 0) sh[w] = v;
    __syncthreads();
    if (w == 0) {
        int nw = (blockDim.x + 63) >> 6;
        v = (lane < nw) ? sh[lane] : 0.f;
        for (int o = 4; o > 0; o >>= 1) v += __shfl_down(v, o);
        if (lane == 0) sh[0] = v;
    }
    __syncthreads();
    return sh[0];
}

__device__ __forceinline__ float blockReduceMax(float v) {
    __shared__ float sh[8];
    int lane = threadIdx.x & 63, w = threadIdx.x >> 6;
    for (int o = 32; o > 0; o >>= 1) v = fmaxf(v, __shfl_down(v, o));
    __syncthreads();
    if (lane == 0) sh[w] = v;
    __syncthreads();
    if (w == 0) {
        int nw = (blockDim.x + 63) >> 6;
        v = (lane < nw) ? sh[lane] : -3.4e38f;
        for (int o = 4; o > 0; o >>= 1) v = fmaxf(v, __shfl_down(v, o));
        if (lane == 0) sh[0] = v;
    }
    __syncthreads();
    return sh[0];
}

__device__ __forceinline__ void bf2x(unsigned int w, float& a, float& b) {
    union { unsigned int u; float f; } x, y;
    x.u = w << 16;
    y.u = w & 0xffff0000u;
    a = x.f;
    b = y.f;
}

// ---------------- kernels ----------------

__global__ void build_csr(const float* __restrict__ adj, int* __restrict__ colIdx,
                          int* __restrict__ deg, int N) {
    int row = blockIdx.x;
    __shared__ int cnt;
    if (threadIdx.x == 0) cnt = 0;
    __syncthreads();
    const float* ar = adj + (size_t)row * N;
    int* outp = colIdx + (size_t)row * MAXDEG;
    for (int j = threadIdx.x; j < N; j += blockDim.x) {
        if (ar[j] > 0.f) {
            int p = atomicAdd(&cnt, 1);
            if (p < MAXDEG) outp[p] = j;
        }
    }
    __syncthreads();
    if (threadIdx.x == 0) deg[row] = cnt < MAXDEG ? cnt : MAXDEG;
}

__global__ void rowsum_kernel(const float* __restrict__ s, float* __restrict__ dv, int N) {
    int row = blockIdx.x;
    const float* r = s + (size_t)row * N;
    float p = 0.f;
    for (int j = threadIdx.x; j < N; j += blockDim.x) p += r[j];
    p = blockReduceSum(p);
    if (threadIdx.x == 0) dv[row] = p;
}

__global__ void hin_kernel(const float* __restrict__ x, const int* __restrict__ obs,
                           const float* __restrict__ theta, __hip_bfloat16* __restrict__ hin,
                           int N, int F) {
    size_t i = (size_t)blockIdx.x * blockDim.x + threadIdx.x;
    if (i >= (size_t)N * F) return;
    int n = (int)(i / F), f = (int)(i % F);
    float v = x[i];
    if (obs[n] == 1) v += theta[f];
    hin[i] = __float2bfloat16(v);
}

// Wt[b][m][k] = bf16(W[b][k][m])
__global__ void conv_wt(const float* __restrict__ W, __hip_bfloat16* __restrict__ Wt,
                        int K, int M) {
    int b = blockIdx.y;
    size_t i = (size_t)blockIdx.x * 256 + threadIdx.x;
    if (i >= (size_t)M * K) return;
    int mm = (int)(i / K), kk = (int)(i % K);
    Wt[(size_t)b * M * K + i] = __float2bfloat16(W[(size_t)b * K * M + (size_t)kk * M + mm]);
}

// C[b] = A[b] @ Bt[b]^T.  A:[N,K] bf16 row-major, Bt:[M,K] bf16 row-major.
__global__ __launch_bounds__(256) void gemm_mfma(
    const __hip_bfloat16* __restrict__ A, const __hip_bfloat16* __restrict__ Bt,
    __hip_bfloat16* __restrict__ C, int N, int K, int M,
    size_t sA, size_t sB, size_t sC) {
    int b = blockIdx.z;
    const unsigned short* Ag = (const unsigned short*)(A + (size_t)b * sA);
    const unsigned short* Bg = (const unsigned short*)(Bt + (size_t)b * sB);
    __hip_bfloat16* Cg = C + (size_t)b * sC;

    __shared__ __align__(16) unsigned short As[64][40];
    __shared__ __align__(16) unsigned short Bs[64][40];

    const int tid = threadIdx.x;
    const int wave = tid >> 6, lane = tid & 63;
    const int row0 = blockIdx.y * 64, col0 = blockIdx.x * 64;
    const int sRow = tid >> 2;
    const int sOff = (tid & 3) * 8;
    const int m = lane & 15, quad = lane >> 4;

    v4f acc[4];
    #pragma unroll
    for (int c = 0; c < 4; c++) acc[c] = (v4f)(0.f);

    for (int k0 = 0; k0 < K; k0 += 32) {
        *(int4*)(&As[sRow][sOff]) =
            *(const int4*)(Ag + (size_t)(row0 + sRow) * K + k0 + sOff);
        *(int4*)(&Bs[sRow][sOff]) =
            *(const int4*)(Bg + (size_t)(col0 + sRow) * K + k0 + sOff);
        __syncthreads();
        v8s af = *(const v8s*)(&As[wave * 16 + m][quad * 8]);
        #pragma unroll
        for (int c = 0; c < 4; c++) {
            v8s bf = *(const v8s*)(&Bs[c * 16 + m][quad * 8]);
            acc[c] = __builtin_amdgcn_mfma_f32_16x16x32_bf16(af, bf, acc[c], 0, 0, 0);
        }
        __syncthreads();
    }
    #pragma unroll
    for (int c = 0; c < 4; c++)
        #pragma unroll
        for (int r = 0; r < 4; r++) {
            int row = row0 + wave * 16 + quad * 4 + r;
            int col = col0 + c * 16 + m;
            Cg[(size_t)row * M + col] = __float2bfloat16(acc[c][r]);
        }
}

// el[b,n] = Wh[b,n,:]·a[b,0:D] ; er[b,n] = Wh[b,n,:]·a[b,D:2D]
__global__ void eler_kernel(const __hip_bfloat16* __restrict__ Wh, const float* __restrict__ a,
                            float* __restrict__ el, float* __restrict__ er,
                            int N, int D, size_t sWh, size_t sa) {
    int row = blockIdx.x, b = blockIdx.y;
    const __hip_bfloat16* w = Wh + (size_t)b * sWh + (size_t)row * D;
    const float* ab = a + (size_t)b * sa;
    float p0 = 0.f, p1 = 0.f;
    for (int d = threadIdx.x; d < D; d += blockDim.x) {
        float v = __bfloat162float(w[d]);
        p0 += v * ab[d];
        p1 += v * ab[D + d];
    }
    p0 = blockReduceSum(p0);
    p1 = blockReduceSum(p1);
    if (threadIdx.x == 0) { el[(size_t)b * N + row] = p0; er[(size_t)b * N + row] = p1; }
}

// Vectorized masked softmax + gather. Block = 256 thr (4 waves), one (row,b).
// Each lane covers 8 consecutive dims (16B load); a wave covers 64/(D/8)
// neighbors per step; 4 waves stride the neighbor list.
template<int D, int ACT>
__global__ __launch_bounds__(256) void attn_vec(
    const unsigned short* __restrict__ Wh, const float* __restrict__ el,
    const float* __restrict__ er, const int* __restrict__ colIdx,
    const int* __restrict__ deg, __hip_bfloat16* __restrict__ out,
    int N, size_t sWh, size_t sOut, int outRowStride) {
    constexpr int LPN = D / 8;        // lanes per neighbor
    constexpr int NPW = 64 / LPN;     // neighbors per wave-step
    constexpr int STRIDE = 4 * NPW;   // per block-step

    int row = blockIdx.x, b = blockIdx.y, tid = threadIdx.x;
    const unsigned short* whb = Wh + (size_t)b * sWh;
    const float* erb = er + (size_t)b * N;
    const float eln = el[(size_t)b * N + row];
    const int dc = deg[row];
    const int* ci = colIdx + (size_t)row * MAXDEG;

    __shared__ float sp[MAXDEG];
    __shared__ int sc[MAXDEG];
    __shared__ float redc[4 * D];

    float mx = -3.4e38f;
    for (int k = tid; k < dc; k += 256) {
        int j = ci[k];
        sc[k] = j;
        float s = eln + erb[j];
        s = (s >= 0.f) ? s : 0.2f * s;        // LeakyReLU(0.2)
        sp[k] = s;
        mx = fmaxf(mx, s);
    }
    mx = blockReduceMax(mx);
    float l = 0.f;
    for (int k = tid; k < dc; k += 256) {
        float p = __expf(sp[k] - mx);
        sp[k] = p;
        l += p;
    }
    l = blockReduceSum(l);
    const float inv = 1.f / l;

    const int wave = tid >> 6, lane = tid & 63;
    const int sub = lane / LPN;       // which neighbor within wave-step
    const int dl = (lane % LPN) * 8;  // dim offset this lane covers

    float acc[8];
    #pragma unroll
    for (int i = 0; i < 8; i++) acc[i] = 0.f;

    for (int k = wave * NPW + sub; k < dc; k += STRIDE) {
        const int j = sc[k];
        const float p = sp[k];
        const uint4 raw = *(const uint4*)(whb + (size_t)j * D + dl);
        float f0, f1, f2, f3, f4, f5, f6, f7;
        bf2x(raw.x, f0, f1);
        bf2x(raw.y, f2, f3);
        bf2x(raw.z, f4, f5);
        bf2x(raw.w, f6, f7);
        acc[0] += p * f0; acc[1] += p * f1;
        acc[2] += p * f2; acc[3] += p * f3;
        acc[4] += p * f4; acc[5] += p * f5;
        acc[6] += p * f6; acc[7] += p * f7;
    }
    // reduce across sub-groups (lanes with same dl differ by multiples of LPN)
    #pragma unroll
    for (int off = LPN; off < 64; off <<= 1)
        #pragma unroll
        for (int i = 0; i < 8; i++) acc[i] += __shfl_xor(acc[i], off);
    __syncthreads();
    if (sub == 0)
        #pragma unroll
        for (int i = 0; i < 8; i++) redc[wave * D + dl + i] = acc[i];
    __syncthreads();
    if (tid < D) {
        float v = (redc[tid] + redc[D + tid] + redc[2 * D + tid] + redc[3 * D + tid]) * inv;
        if (ACT == 1) v = (v > 0.f) ? v : expm1f(v);   // ELU
        out[(size_t)b * sOut + (size_t)row * outRowStride + tid] = __float2bfloat16(v);
    }
}

// D==1 attention (output layer 2)
__global__ void attn_d1(const __hip_bfloat16* __restrict__ Wh, const float* __restrict__ el,
                        const float* __restrict__ er, const int* __restrict__ colIdx,
                        const int* __restrict__ deg, __hip_bfloat16* __restrict__ out, int N) {
    int row = blockIdx.x, tid = threadIdx.x;
    const float eln = el[row];
    const int dc = deg[row];
    const int* ci = colIdx + (size_t)row * MAXDEG;
    __shared__ float sp[MAXDEG];
    __shared__ int sc[MAXDEG];
    float mx = -3.4e38f;
    for (int k = tid; k < dc; k += blockDim.x) {
        int j = ci[k];
        sc[k] = j;
        float s = eln + er[j];
        s = (s >= 0.f) ? s : 0.2f * s;
        sp[k] = s;
        mx = fmaxf(mx, s);
    }
    mx = blockReduceMax(mx);
    float l = 0.f, acc = 0.f;
    for (int k = tid; k < dc; k += blockDim.x) {
        float p = __expf(sp[k] - mx);
        l += p;
        acc += p * __bfloat162float(Wh[sc[k]]);
    }
    l = blockReduceSum(l);
    acc = blockReduceSum(acc);
    if (tid == 0) out[row] = __float2bfloat16(acc / l);
}

// o2Wh[n] = o1o[n,:64] · Wo1[:,0]
__global__ void matvec64_kernel(const __hip_bfloat16* __restrict__ h3,
                                const float* __restrict__ w,
                                __hip_bfloat16* __restrict__ out, int N) {
    int row = blockIdx.x;
    float v = __bfloat162float(h3[(size_t)row * 64 + threadIdx.x]) * w[threadIdx.x];
    for (int o = 32; o > 0; o >>= 1) v += __shfl_down(v, o);
    if (threadIdx.x == 0) out[row] = __float2bfloat16(v);
}

__device__ __forceinline__ float leaky(float x) { return x >= 0.f ? x : 0.2f * x; }

__global__ void degree_nn(const __hip_bfloat16* __restrict__ h4, const float* __restrict__ dv,
                          const float* __restrict__ dW, const float* __restrict__ dW0,
                          const float* __restrict__ dW1, const float* __restrict__ dW01,
                          const float* __restrict__ dW2, const float* __restrict__ dW02,
                          const float* __restrict__ dV, const float* __restrict__ dV0,
                          float* __restrict__ out, int N) {
    int n = blockIdx.x * blockDim.x + threadIdx.x;
    if (n >= N) return;
    float h = __bfloat162float(h4[n]);
    h = (h > 0.f) ? h : expm1f(h);            // elu
    float d = dv[n];
    float t0[10], t1[20], t2[10];
    #pragma unroll
    for (int i = 0; i < 10; i++)
        t0[i] = leaky(h * dW[i] + d * dW[10 + i] + dW0[i]);
    #pragma unroll
    for (int j = 0; j < 20; j++) {
        float s = dW01[j];
        #pragma unroll
        for (int i = 0; i < 10; i++) s += t0[i] * dW1[i * 20 + j];
        t1[j] = leaky(s);
    }
    #pragma unroll
    for (int j = 0; j < 10; j++) {
        float s = dW02[j];
        #pragma unroll
        for (int i = 0; i < 20; i++) s += t1[i] * dW2[i * 10 + j];
        t2[j] = leaky(s);
    }
    float o = dV0[0];
    #pragma unroll
    for (int i = 0; i < 10; i++) o += t2[i] * dV[i];
    out[n] = leaky(o);
}

// ---------------- launch ----------------
extern "C" void kernel_launch(void* const* d_in, const int* in_sizes, int n_in,
                              void* d_out, int out_size, void* d_ws, size_t ws_size,
                              hipStream_t stream) {
    const int N = 4096, F = 512, H = 4, D1 = 256, O1 = 64;
    const float* x     = (const float*)d_in[0];
    const float* adj   = (const float*)d_in[1];
    const int*   obs   = (const int*)  d_in[2];
    const float* s_mat = (const float*)d_in[3];
    const float* theta = (const float*)d_in[4];
    const float* Wh0   = (const float*)d_in[5];
    const float* ah0   = (const float*)d_in[6];
    const float* Wh1   = (const float*)d_in[7];
    const float* ah1   = (const float*)d_in[8];
    const float* Wo0   = (const float*)d_in[9];
    const float* ao0   = (const float*)d_in[10];
    const float* Wo1   = (const float*)d_in[11];
    const float* ao1   = (const float*)d_in[12];
    const float* dWp   = (const float*)d_in[13];
    const float* dW0p  = (const float*)d_in[14];
    const float* dW1p  = (const float*)d_in[15];
    const float* dW01p = (const float*)d_in[16];
    const float* dW2p  = (const float*)d_in[17];
    const float* dW02p = (const float*)d_in[18];
    const float* dVp   = (const float*)d_in[19];
    const float* dV0p  = (const float*)d_in[20];
    float* outp = (float*)d_out;

    char* ws = (char*)d_ws;
    auto alloc = [&](size_t bytes) {
        char* p = ws;
        ws += (bytes + 255) & ~(size_t)255;
        return p;
    };
    typedef __hip_bfloat16 bf;
    bf* hin   = (bf*)alloc((size_t)N * F * 2);
    bf* whA   = (bf*)alloc((size_t)H * N * D1 * 2);
    bf* hb    = (bf*)alloc((size_t)H * N * D1 * 2);
    bf* hcat  = (bf*)alloc((size_t)N * H * D1 * 2);
    bf* o1Wh  = (bf*)alloc((size_t)N * O1 * 2);
    bf* o1o   = (bf*)alloc((size_t)N * O1 * 2);
    bf* o2Wh  = (bf*)alloc((size_t)N * 2);
    bf* o2o   = (bf*)alloc((size_t)N * 2);
    bf* Wh0t  = (bf*)alloc((size_t)H * F * D1 * 2);
    bf* Wh1t  = (bf*)alloc((size_t)H * D1 * D1 * 2);
    bf* Wo0t  = (bf*)alloc((size_t)H * D1 * O1 * 2);
    float* el = (float*)alloc((size_t)H * N * 4);
    float* er = (float*)alloc((size_t)H * N * 4);
    float* dv = (float*)alloc((size_t)N * 4);
    int* colIdx = (int*)alloc((size_t)N * MAXDEG * 4);
    int* deg    = (int*)alloc((size_t)N * 4);

    build_csr<<<N, 256, 0, stream>>>(adj, colIdx, deg, N);
    rowsum_kernel<<<N, 256, 0, stream>>>(s_mat, dv, N);
    hin_kernel<<<(N * F + 255) / 256, 256, 0, stream>>>(x, obs, theta, hin, N, F);
    conv_wt<<<dim3((F * D1 + 255) / 256, H), 256, 0, stream>>>(Wh0, Wh0t, F, D1);
    conv_wt<<<dim3((D1 * D1 + 255) / 256, H), 256, 0, stream>>>(Wh1, Wh1t, D1, D1);
    conv_wt<<<dim3((H * D1 * O1 + 255) / 256, 1), 256, 0, stream>>>(Wo0, Wo0t, H * D1, O1);

    // ----- multi-head layer 1 (D=256, elu) -----
    gemm_mfma<<<dim3(D1 / 64, N / 64, H), 256, 0, stream>>>(
        hin, Wh0t, whA, N, F, D1, 0, (size_t)D1 * F, (size_t)N * D1);
    eler_kernel<<<dim3(N, H), 256, 0, stream>>>(whA, ah0, el, er, N, D1,
        (size_t)N * D1, (size_t)2 * D1);
    attn_vec<256, 1><<<dim3(N, H), 256, 0, stream>>>(
        (const unsigned short*)whA, el, er, colIdx, deg, hb,
        N, (size_t)N * D1, (size_t)N * D1, D1);

    // ----- multi-head layer 2 (D=256, elu) -> hcat interleaved -----
    gemm_mfma<<<dim3(D1 / 64, N / 64, H), 256, 0, stream>>>(
        hb, Wh1t, whA, N, D1, D1, (size_t)N * D1, (size_t)D1 * D1, (size_t)N * D1);
    eler_kernel<<<dim3(N, H), 256, 0, stream>>>(whA, ah1, el, er, N, D1,
        (size_t)N * D1, (size_t)2 * D1);
    attn_vec<256, 1><<<dim3(N, H), 256, 0, stream>>>(
        (const unsigned short*)whA, el, er, colIdx, deg, hcat,
        N, (size_t)N * D1, (size_t)D1, H * D1);

    // ----- output layer 1 (D=64, no act) -----
    gemm_mfma<<<dim3(O1 / 64, N / 64, 1), 256, 0, stream>>>(
        hcat, Wo0t, o1Wh, N, H * D1, O1, 0, 0, 0);
    eler_kernel<<<dim3(N, 1), 64, 0, stream>>>(o1Wh, ao0, el, er, N, O1, 0, 0);
    attn_vec<64, 0><<<dim3(N, 1), 256, 0, stream>>>(
        (const unsigned short*)o1Wh, el, er, colIdx, deg, o1o, N, 0, 0, O1);

    // ----- output layer 2 (D=1, no act) -----
    matvec64_kernel<<<N, 64, 0, stream>>>(o1o, Wo1, o2Wh, N);
    eler_kernel<<<dim3(N, 1), 64, 0, stream>>>(o2Wh, ao1, el, er, N, 1, 0, 0);
    attn_d1<<<N, 256, 0, stream>>>(o2Wh, el, er, colIdx, deg, o2o, N);

    // ----- elu + degreeNN -----
    degree_nn<<<(N + 255) / 256, 256, 0, stream>>>(o2o, dv, dWp, dW0p, dW1p,
        dW01p, dW2p, dW02p, dVp, dV0p, outp, N);
}

// Round 4
// 443.558 us; speedup vs baseline: 2.1008x; 1.1087x over previous
//
#include <hip/hip_runtime.h>
#include <hip/hip_bf16.h>
#include <math.h>

#define MAXDEG 512

typedef short v8s __attribute__((ext_vector_type(8)));
typedef float v4f __attribute__((ext_vector_type(4)));
typedef float v2f __attribute__((ext_vector_type(2)));

// ---------------- block reduce helpers ----------------
__device__ __forceinline__ float blockReduceSum(float v) {
    __shared__ float sh[8];
    int lane = threadIdx.x & 63, w = threadIdx.x >> 6;
    for (int o = 32; o > 0; o >>= 1) v += __shfl_down(v, o);
    __syncthreads();
    if (lane == 0) sh[w] = v;
    __syncthreads();
    if (w == 0) {
        int nw = (blockDim.x + 63) >> 6;
        v = (lane < nw) ? sh[lane] : 0.f;
        for (int o = 4; o > 0; o >>= 1) v += __shfl_down(v, o);
        if (lane == 0) sh[0] = v;
    }
    __syncthreads();
    return sh[0];
}

__device__ __forceinline__ float blockReduceMax(float v) {
    __shared__ float sh[8];
    int lane = threadIdx.x & 63, w = threadIdx.x >> 6;
    for (int o = 32; o > 0; o >>= 1) v = fmaxf(v, __shfl_down(v, o));
    __syncthreads();
    if (lane == 0) sh[w] = v;
    __syncthreads();
    if (w == 0) {
        int nw = (blockDim.x + 63) >> 6;
        v = (lane < nw) ? sh[lane] : -3.4e38f;
        for (int o = 4; o > 0; o >>= 1) v = fmaxf(v, __shfl_down(v, o));
        if (lane == 0) sh[0] = v;
    }
    __syncthreads();
    return sh[0];
}

__device__ __forceinline__ v2f bf2f(unsigned int u) {
    union { unsigned int u; float f; } lo, hi;
    lo.u = u << 16;
    hi.u = u & 0xffff0000u;
    return (v2f){lo.f, hi.f};
}

__device__ __forceinline__ void acc_add(v2f* a, float p, const uint4& r) {
    v2f pp = (v2f){p, p};
    a[0] += pp * bf2f(r.x);
    a[1] += pp * bf2f(r.y);
    a[2] += pp * bf2f(r.z);
    a[3] += pp * bf2f(r.w);
}

// ---------------- kernels ----------------

__global__ void zero_f32(float* __restrict__ p, int n) {
    int i = blockIdx.x * 256 + threadIdx.x;
    if (i < n) p[i] = 0.f;
}

// CSR build + s_mat row sum in one pass (both scan one 67MB row-block).
__global__ void csr_rowsum(const float* __restrict__ adj, const float* __restrict__ s,
                           int* __restrict__ colIdx, int* __restrict__ deg,
                           float* __restrict__ dv, int N) {
    int row = blockIdx.x;
    __shared__ int cnt;
    if (threadIdx.x == 0) cnt = 0;
    __syncthreads();
    const float* ar = adj + (size_t)row * N;
    const float* sr = s + (size_t)row * N;
    int* outp = colIdx + (size_t)row * MAXDEG;
    float psum = 0.f;
    for (int j = threadIdx.x; j < N; j += blockDim.x) {
        psum += sr[j];
        if (ar[j] > 0.f) {
            int p = atomicAdd(&cnt, 1);
            if (p < MAXDEG) outp[p] = j;
        }
    }
    psum = blockReduceSum(psum);
    __syncthreads();
    if (threadIdx.x == 0) {
        deg[row] = cnt < MAXDEG ? cnt : MAXDEG;
        dv[row] = psum;
    }
}

__global__ void hin_kernel(const float* __restrict__ x, const int* __restrict__ obs,
                           const float* __restrict__ theta, __hip_bfloat16* __restrict__ hin,
                           int NF) {
    int i = blockIdx.x * 256 + threadIdx.x;
    if (i >= NF) return;
    int n = i >> 9, f = i & 511;   // F = 512
    float v = x[i];
    if (obs[n] == 1) v += theta[f];
    hin[i] = __float2bfloat16(v);
}

// Wt[b][m][k] = bf16(W[b][k][m])
__global__ void conv_wt(const float* __restrict__ W, __hip_bfloat16* __restrict__ Wt,
                        int K, int M) {
    int b = blockIdx.y;
    size_t i = (size_t)blockIdx.x * 256 + threadIdx.x;
    if (i >= (size_t)M * K) return;
    int mm = (int)(i / K), kk = (int)(i % K);
    Wt[(size_t)b * M * K + i] = __float2bfloat16(W[(size_t)b * K * M + (size_t)kk * M + mm]);
}

// C[b] = A[b] @ Bt[b]^T with fused el/er epilogue (atomicAdd partials).
// A:[N,K] bf16 row-major, Bt:[M,K] bf16 row-major, C:[N,M] bf16.
// el[b*N+r] += sum_cols Wh[r][col]*aVec[col]; er with aVec[M+col].
__global__ __launch_bounds__(256) void gemm_mfma(
    const __hip_bfloat16* __restrict__ A, const __hip_bfloat16* __restrict__ Bt,
    __hip_bfloat16* __restrict__ C, int N, int K, int M,
    size_t sA, size_t sB, size_t sC,
    const float* __restrict__ aVec, size_t aStride,
    float* __restrict__ el, float* __restrict__ er) {
    int b = blockIdx.z;
    const unsigned short* Ag = (const unsigned short*)(A + (size_t)b * sA);
    const unsigned short* Bg = (const unsigned short*)(Bt + (size_t)b * sB);
    __hip_bfloat16* Cg = C + (size_t)b * sC;
    const float* av = aVec + (size_t)b * aStride;

    __shared__ __align__(16) unsigned short As[64][40];
    __shared__ __align__(16) unsigned short Bs[64][40];

    const int tid = threadIdx.x;
    const int wave = tid >> 6, lane = tid & 63;
    const int row0 = blockIdx.y * 64, col0 = blockIdx.x * 64;
    const int sRow = tid >> 2;
    const int sOff = (tid & 3) * 8;
    const int m = lane & 15, quad = lane >> 4;

    v4f acc[4];
    #pragma unroll
    for (int c = 0; c < 4; c++) acc[c] = (v4f)(0.f);

    for (int k0 = 0; k0 < K; k0 += 32) {
        *(int4*)(&As[sRow][sOff]) =
            *(const int4*)(Ag + (size_t)(row0 + sRow) * K + k0 + sOff);
        *(int4*)(&Bs[sRow][sOff]) =
            *(const int4*)(Bg + (size_t)(col0 + sRow) * K + k0 + sOff);
        __syncthreads();
        v8s af = *(const v8s*)(&As[wave * 16 + m][quad * 8]);
        #pragma unroll
        for (int c = 0; c < 4; c++) {
            v8s bf = *(const v8s*)(&Bs[c * 16 + m][quad * 8]);
            acc[c] = __builtin_amdgcn_mfma_f32_16x16x32_bf16(af, bf, acc[c], 0, 0, 0);
        }
        __syncthreads();
    }
    // C store
    #pragma unroll
    for (int c = 0; c < 4; c++)
        #pragma unroll
        for (int r = 0; r < 4; r++) {
            int row = row0 + wave * 16 + quad * 4 + r;
            int col = col0 + c * 16 + m;
            Cg[(size_t)row * M + col] = __float2bfloat16(acc[c][r]);
        }
    // fused el/er partials
    float ael[4], aer[4];
    #pragma unroll
    for (int c = 0; c < 4; c++) {
        ael[c] = av[col0 + c * 16 + m];
        aer[c] = av[M + col0 + c * 16 + m];
    }
    #pragma unroll
    for (int r = 0; r < 4; r++) {
        float pel = 0.f, per_ = 0.f;
        #pragma unroll
        for (int c = 0; c < 4; c++) {
            pel += acc[c][r] * ael[c];
            per_ += acc[c][r] * aer[c];
        }
        #pragma unroll
        for (int off = 1; off < 16; off <<= 1) {
            pel += __shfl_xor(pel, off);
            per_ += __shfl_xor(per_, off);
        }
        if (m == 0) {
            int row = row0 + wave * 16 + quad * 4 + r;
            atomicAdd(&el[(size_t)b * N + row], pel);
            atomicAdd(&er[(size_t)b * N + row], per_);
        }
    }
}

// Vectorized masked softmax + gather. Block = 256 thr (4 waves).
// HEADS==4: 1-D grid 16384 with XCD clustering: head h -> blocks with
// blk%8 in {2h,2h+1}, so each head's 2MB Wh is L2-resident on 2 XCDs.
template<int D, int ACT, int HEADS>
__global__ __launch_bounds__(256) void attn_vec(
    const unsigned short* __restrict__ Wh, const float* __restrict__ el,
    const float* __restrict__ er, const int* __restrict__ colIdx,
    const int* __restrict__ deg, __hip_bfloat16* __restrict__ out,
    int N, size_t sWh, size_t sOut, int outRowStride) {
    constexpr int LPN = D / 8;        // lanes per neighbor
    constexpr int NPW = 64 / LPN;     // neighbors per wave-step
    constexpr int STRIDE = 4 * NPW;   // per block-step

    int b, row;
    if (HEADS == 4) {
        int blk = blockIdx.x;
        b = (blk & 7) >> 1;
        row = ((blk >> 3) << 1) | (blk & 1);
    } else {
        b = 0;
        row = blockIdx.x;
    }
    const int tid = threadIdx.x;
    const unsigned short* whb = Wh + (size_t)b * sWh;
    const float* erb = er + (size_t)b * N;
    const float eln = el[(size_t)b * N + row];
    const int dc = deg[row];
    const int* ci = colIdx + (size_t)row * MAXDEG;

    __shared__ float2 spc[MAXDEG];    // {score->p, asint(j)}
    __shared__ float redc[4 * D];

    float mx = -3.4e38f;
    for (int k = tid; k < dc; k += 256) {
        int j = ci[k];
        float s = eln + erb[j];
        s = fmaxf(s, 0.2f * s);               // LeakyReLU(0.2)
        spc[k] = make_float2(s, __int_as_float(j));
        mx = fmaxf(mx, s);
    }
    mx = blockReduceMax(mx);
    float l = 0.f;
    for (int k = tid; k < dc; k += 256) {
        float p = __expf(spc[k].x - mx);
        spc[k].x = p;
        l += p;
    }
    l = blockReduceSum(l);
    const float inv = 1.f / l;

    const int wave = tid >> 6, lane = tid & 63;
    const int sub = lane / LPN;
    const int dl = (lane % LPN) * 8;
    const unsigned short* wp = whb + dl;

    v2f a0[4], a1[4];
    #pragma unroll
    for (int i = 0; i < 4; i++) { a0[i] = (v2f)(0.f); a1[i] = (v2f)(0.f); }

    for (int k = wave * NPW + sub; k < dc; k += 2 * STRIDE) {
        float2 pc0 = spc[k];
        int j0 = __float_as_int(pc0.y);
        const uint4 r0 = *(const uint4*)(wp + (size_t)j0 * D);
        int k1 = k + STRIDE;
        float2 pc1 = (k1 < dc) ? spc[k1] : make_float2(0.f, pc0.y);
        int j1 = __float_as_int(pc1.y);
        const uint4 r1 = *(const uint4*)(wp + (size_t)j1 * D);
        acc_add(a0, pc0.x, r0);
        acc_add(a1, pc1.x, r1);
    }
    #pragma unroll
    for (int i = 0; i < 4; i++) a0[i] += a1[i];
    // reduce across sub-groups
    #pragma unroll
    for (int off = LPN; off < 64; off <<= 1)
        #pragma unroll
        for (int i = 0; i < 4; i++) {
            a0[i][0] += __shfl_xor(a0[i][0], off);
            a0[i][1] += __shfl_xor(a0[i][1], off);
        }
    __syncthreads();
    if (sub == 0)
        #pragma unroll
        for (int i = 0; i < 4; i++)
            *(float2*)(&redc[wave * D + dl + 2 * i]) = make_float2(a0[i][0], a0[i][1]);
    __syncthreads();
    if (tid < D) {
        float v = (redc[tid] + redc[D + tid] + redc[2 * D + tid] + redc[3 * D + tid]) * inv;
        if (ACT == 1) v = (v > 0.f) ? v : expm1f(v);   // ELU
        out[(size_t)b * sOut + (size_t)row * outRowStride + tid] = __float2bfloat16(v);
    }
}

// D==1 attention (output layer 2)
__global__ void attn_d1(const __hip_bfloat16* __restrict__ Wh, const float* __restrict__ el,
                        const float* __restrict__ er, const int* __restrict__ colIdx,
                        const int* __restrict__ deg, __hip_bfloat16* __restrict__ out, int N) {
    int row = blockIdx.x, tid = threadIdx.x;
    const float eln = el[row];
    const int dc = deg[row];
    const int* ci = colIdx + (size_t)row * MAXDEG;
    __shared__ float sp[MAXDEG];
    __shared__ int sc[MAXDEG];
    float mx = -3.4e38f;
    for (int k = tid; k < dc; k += blockDim.x) {
        int j = ci[k];
        sc[k] = j;
        float s = eln + er[j];
        s = fmaxf(s, 0.2f * s);
        sp[k] = s;
        mx = fmaxf(mx, s);
    }
    mx = blockReduceMax(mx);
    float l = 0.f, acc = 0.f;
    for (int k = tid; k < dc; k += blockDim.x) {
        float p = __expf(sp[k] - mx);
        l += p;
        acc += p * __bfloat162float(Wh[sc[k]]);
    }
    l = blockReduceSum(l);
    acc = blockReduceSum(acc);
    if (tid == 0) out[row] = __float2bfloat16(acc / l);
}

// o2Wh[n] = o1o[n,:64]·Wo1[:,0]; fused el4/er4 = o2Wh*ao1[0/1]
__global__ void matvec64_kernel(const __hip_bfloat16* __restrict__ h3,
                                const float* __restrict__ w,
                                const float* __restrict__ ao1,
                                __hip_bfloat16* __restrict__ out,
                                float* __restrict__ el4, float* __restrict__ er4, int N) {
    int row = blockIdx.x;
    float v = __bfloat162float(h3[(size_t)row * 64 + threadIdx.x]) * w[threadIdx.x];
    for (int o = 32; o > 0; o >>= 1) v += __shfl_down(v, o);
    if (threadIdx.x == 0) {
        out[row] = __float2bfloat16(v);
        el4[row] = v * ao1[0];
        er4[row] = v * ao1[1];
    }
}

__device__ __forceinline__ float leaky(float x) { return x >= 0.f ? x : 0.2f * x; }

__global__ void degree_nn(const __hip_bfloat16* __restrict__ h4, const float* __restrict__ dv,
                          const float* __restrict__ dW, const float* __restrict__ dW0,
                          const float* __restrict__ dW1, const float* __restrict__ dW01,
                          const float* __restrict__ dW2, const float* __restrict__ dW02,
                          const float* __restrict__ dV, const float* __restrict__ dV0,
                          float* __restrict__ out, int N) {
    int n = blockIdx.x * blockDim.x + threadIdx.x;
    if (n >= N) return;
    float h = __bfloat162float(h4[n]);
    h = (h > 0.f) ? h : expm1f(h);            // elu
    float d = dv[n];
    float t0[10], t1[20], t2[10];
    #pragma unroll
    for (int i = 0; i < 10; i++)
        t0[i] = leaky(h * dW[i] + d * dW[10 + i] + dW0[i]);
    #pragma unroll
    for (int j = 0; j < 20; j++) {
        float s = dW01[j];
        #pragma unroll
        for (int i = 0; i < 10; i++) s += t0[i] * dW1[i * 20 + j];
        t1[j] = leaky(s);
    }
    #pragma unroll
    for (int j = 0; j < 10; j++) {
        float s = dW02[j];
        #pragma unroll
        for (int i = 0; i < 20; i++) s += t1[i] * dW2[i * 10 + j];
        t2[j] = leaky(s);
    }
    float o = dV0[0];
    #pragma unroll
    for (int i = 0; i < 10; i++) o += t2[i] * dV[i];
    out[n] = leaky(o);
}

// ---------------- launch ----------------
extern "C" void kernel_launch(void* const* d_in, const int* in_sizes, int n_in,
                              void* d_out, int out_size, void* d_ws, size_t ws_size,
                              hipStream_t stream) {
    const int N = 4096, F = 512, H = 4, D1 = 256, O1 = 64;
    const float* x     = (const float*)d_in[0];
    const float* adj   = (const float*)d_in[1];
    const int*   obs   = (const int*)  d_in[2];
    const float* s_mat = (const float*)d_in[3];
    const float* theta = (const float*)d_in[4];
    const float* Wh0   = (const float*)d_in[5];
    const float* ah0   = (const float*)d_in[6];
    const float* Wh1   = (const float*)d_in[7];
    const float* ah1   = (const float*)d_in[8];
    const float* Wo0   = (const float*)d_in[9];
    const float* ao0   = (const float*)d_in[10];
    const float* Wo1   = (const float*)d_in[11];
    const float* ao1   = (const float*)d_in[12];
    const float* dWp   = (const float*)d_in[13];
    const float* dW0p  = (const float*)d_in[14];
    const float* dW1p  = (const float*)d_in[15];
    const float* dW01p = (const float*)d_in[16];
    const float* dW2p  = (const float*)d_in[17];
    const float* dW02p = (const float*)d_in[18];
    const float* dVp   = (const float*)d_in[19];
    const float* dV0p  = (const float*)d_in[20];
    float* outp = (float*)d_out;

    char* ws = (char*)d_ws;
    auto alloc = [&](size_t bytes) {
        char* p = ws;
        ws += (bytes + 255) & ~(size_t)255;
        return p;
    };
    typedef __hip_bfloat16 bf;
    bf* hin   = (bf*)alloc((size_t)N * F * 2);
    bf* whA   = (bf*)alloc((size_t)H * N * D1 * 2);
    bf* hb    = (bf*)alloc((size_t)H * N * D1 * 2);
    bf* hcat  = (bf*)alloc((size_t)N * H * D1 * 2);
    bf* o1Wh  = (bf*)alloc((size_t)N * O1 * 2);
    bf* o1o   = (bf*)alloc((size_t)N * O1 * 2);
    bf* o2Wh  = (bf*)alloc((size_t)N * 2);
    bf* o2o   = (bf*)alloc((size_t)N * 2);
    bf* Wh0t  = (bf*)alloc((size_t)H * F * D1 * 2);
    bf* Wh1t  = (bf*)alloc((size_t)H * D1 * D1 * 2);
    bf* Wo0t  = (bf*)alloc((size_t)H * D1 * O1 * 2);
    // el/er stage buffers (contiguous for one-shot zeroing)
    int elerN = 4 * H * N + 2 * N;
    float* elerZ = (float*)alloc((size_t)elerN * 4);
    float* el1 = elerZ;
    float* er1 = el1 + H * N;
    float* el2 = er1 + H * N;
    float* er2 = el2 + H * N;
    float* el3 = er2 + H * N;
    float* er3 = el3 + N;
    float* el4 = (float*)alloc((size_t)N * 4);
    float* er4 = (float*)alloc((size_t)N * 4);
    float* dv  = (float*)alloc((size_t)N * 4);
    int* colIdx = (int*)alloc((size_t)N * MAXDEG * 4);
    int* deg    = (int*)alloc((size_t)N * 4);

    zero_f32<<<(elerN + 255) / 256, 256, 0, stream>>>(elerZ, elerN);
    csr_rowsum<<<N, 256, 0, stream>>>(adj, s_mat, colIdx, deg, dv, N);
    hin_kernel<<<(N * F + 255) / 256, 256, 0, stream>>>(x, obs, theta, hin, N * F);
    conv_wt<<<dim3((F * D1 + 255) / 256, H), 256, 0, stream>>>(Wh0, Wh0t, F, D1);
    conv_wt<<<dim3((D1 * D1 + 255) / 256, H), 256, 0, stream>>>(Wh1, Wh1t, D1, D1);
    conv_wt<<<dim3((H * D1 * O1 + 255) / 256, 1), 256, 0, stream>>>(Wo0, Wo0t, H * D1, O1);

    // ----- multi-head layer 1 (D=256, elu) -----
    gemm_mfma<<<dim3(D1 / 64, N / 64, H), 256, 0, stream>>>(
        hin, Wh0t, whA, N, F, D1, 0, (size_t)D1 * F, (size_t)N * D1,
        ah0, (size_t)2 * D1, el1, er1);
    attn_vec<256, 1, 4><<<N * H, 256, 0, stream>>>(
        (const unsigned short*)whA, el1, er1, colIdx, deg, hb,
        N, (size_t)N * D1, (size_t)N * D1, D1);

    // ----- multi-head layer 2 (D=256, elu) -> hcat interleaved -----
    gemm_mfma<<<dim3(D1 / 64, N / 64, H), 256, 0, stream>>>(
        hb, Wh1t, whA, N, D1, D1, (size_t)N * D1, (size_t)D1 * D1, (size_t)N * D1,
        ah1, (size_t)2 * D1, el2, er2);
    attn_vec<256, 1, 4><<<N * H, 256, 0, stream>>>(
        (const unsigned short*)whA, el2, er2, colIdx, deg, hcat,
        N, (size_t)N * D1, (size_t)D1, H * D1);

    // ----- output layer 1 (D=64, no act) -----
    gemm_mfma<<<dim3(O1 / 64, N / 64, 1), 256, 0, stream>>>(
        hcat, Wo0t, o1Wh, N, H * D1, O1, 0, 0, 0,
        ao0, 0, el3, er3);
    attn_vec<64, 0, 1><<<N, 256, 0, stream>>>(
        (const unsigned short*)o1Wh, el3, er3, colIdx, deg, o1o, N, 0, 0, O1);

    // ----- output layer 2 (D=1, no act) -----
    matvec64_kernel<<<N, 64, 0, stream>>>(o1o, Wo1, ao1, o2Wh, el4, er4, N);
    attn_d1<<<N, 256, 0, stream>>>(o2Wh, el4, er4, colIdx, deg, o2o, N);

    // ----- elu + degreeNN -----
    degree_nn<<<(N + 255) / 256, 256, 0, stream>>>(o2o, dv, dWp, dW0p, dW1p,
        dW01p, dW2p, dW02p, dVp, dV0p, outp, N);
}